// Round 11
// baseline (476.151 us; speedup 1.0000x reference)
//
#include <hip/hip_runtime.h>
#include <hip/hip_bf16.h>
#include <stdint.h>

#define S_LEN 2048
#define NHEAD 16
#define BATCH 4

typedef __attribute__((ext_vector_type(8))) short short8;
typedef __attribute__((ext_vector_type(4))) float f32x4;
typedef __attribute__((ext_vector_type(4))) unsigned short u16x4;

__device__ float2 g_tab[131072];  // [0..64K) Q table (pre-scaled), [64K..128K) K table

__device__ __forceinline__ unsigned short f2bf(float f) {
  union { float f; uint32_t u; } a; a.f = f;
  uint32_t r = (a.u + 0x7fff + ((a.u >> 16) & 1)) >> 16;
  return (unsigned short)r;
}
__device__ __forceinline__ float bf2f(unsigned short u) {
  union { uint32_t u; float f; } a; a.u = ((uint32_t)u) << 16;
  return a.f;
}
__device__ __forceinline__ uint32_t pk2bf(float a, float b) {
  union { __hip_bfloat162 h; uint32_t u; } cv;
  cv.h = __float22bfloat162_rn(float2{a, b});
  return cv.u;
}

__device__ __forceinline__ void gload16(const void* g, void* l) {
  __builtin_amdgcn_global_load_lds(
      (const __attribute__((address_space(1))) void*)g,
      (__attribute__((address_space(3))) void*)l, 16, 0, 0);
}

// rotate 8 bf16 (4 adjacent pairs) by table entries t01 (pairs 0,1) t23 (pairs 2,3)
__device__ __forceinline__ short8 rope8(short8 v, float4 t01, float4 t23) {
  float x0 = bf2f((unsigned short)v[0]), x1 = bf2f((unsigned short)v[1]);
  float x2 = bf2f((unsigned short)v[2]), x3 = bf2f((unsigned short)v[3]);
  float x4 = bf2f((unsigned short)v[4]), x5 = bf2f((unsigned short)v[5]);
  float x6 = bf2f((unsigned short)v[6]), x7 = bf2f((unsigned short)v[7]);
  union { uint32_t u[4]; short8 v; } o;
  o.u[0] = pk2bf(t01.x * x0 - t01.y * x1, t01.y * x0 + t01.x * x1);
  o.u[1] = pk2bf(t01.z * x2 - t01.w * x3, t01.w * x2 + t01.z * x3);
  o.u[2] = pk2bf(t23.x * x4 - t23.y * x5, t23.y * x4 + t23.x * x5);
  o.u[3] = pk2bf(t23.z * x6 - t23.w * x7, t23.w * x6 + t23.z * x7);
  return o.v;
}

// ---------------- prep: x->bf16, weights->bf16, rope tables, one launch -------------
__global__ void k_prep(const float* __restrict__ x, const float* __restrict__ wq,
                       const float* __restrict__ wk, const float* __restrict__ wv,
                       const float* __restrict__ wo, const int* __restrict__ pos,
                       unsigned short* __restrict__ xb, unsigned short* __restrict__ wdst) {
  int bid = blockIdx.x;
  if (bid < 8192) {
    int i = bid * 256 + threadIdx.x;
    float4 v = ((const float4*)x)[i];
    union { uint32_t u[2]; u16x4 v; } o;
    o.u[0] = pk2bf(v.x, v.y);
    o.u[1] = pk2bf(v.z, v.w);
    ((u16x4*)xb)[i] = o.v;
  } else if (bid < 12288) {
    int i = (bid - 8192) * 256 + threadIdx.x;
    int r = i >> 18;
    const float* s = r == 0 ? wq : r == 1 ? wk : r == 2 ? wv : wo;
    float4 v = ((const float4*)s)[i & 0x3FFFF];
    union { uint32_t u[2]; u16x4 v; } o;
    o.u[0] = pk2bf(v.x, v.y);
    o.u[1] = pk2bf(v.z, v.w);
    ((u16x4*)wdst)[i] = o.v;
  } else {
    int i = (bid - 12288) * 256 + threadIdx.x;
    int s = i >> 5, p = i & 31;
    float fp = (float)pos[s];
    float inv = exp2f(-(float)p * 0.41524101186092029f);
    float sn, cs;
    __sincosf(fp * inv, &sn, &cs);
    const float SCL = 0.18033688011112042f;  // (1/8) * log2(e)
    g_tab[i] = float2{cs * SCL, sn * SCL};
    g_tab[65536 + i] = float2{cs, sn};
  }
}

// ---------------- NT GEMM, XCD-swizzled, 1-deep prefetch double-buffer --------------
template<int OUTF32>
__global__ __launch_bounds__(256) void k_gemm_nt(
    const unsigned short* __restrict__ A, const unsigned short* __restrict__ B,
    void* __restrict__ Cp, int K, int ldc, int gx)
{
  __shared__ unsigned short lA[2][128 * 64];
  __shared__ unsigned short lB[2][128 * 64];
  const int tid = threadIdx.x;
  const int w = tid >> 6, lane = tid & 63;
  const int wm = w >> 1, wn = w & 1;
  const int l15 = lane & 15, lg = lane >> 4;
  const int nwg = (int)gridDim.x, slot = (int)blockIdx.x;
  const int f = (slot & 7) * (nwg >> 3) + (slot >> 3);
  const int row0 = (f / gx) * 128, col0 = (f % gx) * 128;

  f32x4 acc[4][4] = {};
  const size_t rsb = (size_t)K * 2;

  auto stage = [&](int buf, int k0) {
#pragma unroll
    for (int it = 0; it < 4; ++it) {
      int fb = w * 4096 + it * 1024 + lane * 16;
      int r = fb >> 7, cb = fb & 127;
      gload16((const char*)A + (size_t)(row0 + r) * rsb + k0 * 2 + cb,
              (char*)(&lA[buf][0]) + (w * 4096 + it * 1024));
      gload16((const char*)B + (size_t)(col0 + r) * rsb + k0 * 2 + cb,
              (char*)(&lB[buf][0]) + (w * 4096 + it * 1024));
    }
  };

  const int nk = K >> 6;
  stage(0, 0);
  __syncthreads();

  for (int t = 0; t < nk; ++t) {
    const int cur = t & 1;
    if (t + 1 < nk) stage(cur ^ 1, (t + 1) * 64);

#pragma unroll
    for (int ks = 0; ks < 2; ++ks) {
      short8 af[4], bg[4];
#pragma unroll
      for (int i = 0; i < 4; ++i) {
        int rowa = wm * 64 + i * 16 + l15;
        af[i] = *(const short8*)((const char*)(&lA[cur][0]) + rowa * 128 + ks * 64 + lg * 16);
        int rowb = wn * 64 + i * 16 + l15;
        bg[i] = *(const short8*)((const char*)(&lB[cur][0]) + rowb * 128 + ks * 64 + lg * 16);
      }
#pragma unroll
      for (int i = 0; i < 4; ++i)
#pragma unroll
        for (int j = 0; j < 4; ++j)
          acc[i][j] = __builtin_amdgcn_mfma_f32_16x16x32_bf16(af[i], bg[j], acc[i][j], 0, 0, 0);
    }
    __syncthreads();
  }

#pragma unroll
  for (int i = 0; i < 4; ++i)
#pragma unroll
    for (int j = 0; j < 4; ++j) {
      int col = col0 + wn * 64 + j * 16 + l15;
#pragma unroll
      for (int r = 0; r < 4; ++r) {
        int row = row0 + wm * 64 + i * 16 + lg * 4 + r;
        float v = acc[i][j][r];
        if (OUTF32) ((float*)Cp)[(size_t)row * ldc + col] = v;
        else ((unsigned short*)Cp)[(size_t)row * ldc + col] = f2bf(v);
      }
    }
}

// ---------------- RoPE apply, K only (Q is roped in-register inside k_attn) ---------
__global__ void k_rope(unsigned short* __restrict__ qkv) {
  int idx = blockIdx.x * 256 + threadIdx.x;   // 1M threads: 8192 rows x 128 quads
  int row = idx >> 7;
  int cq = idx & 127;
  int s = row & (S_LEN - 1);
  const float4* tb = (const float4*)&g_tab[65536 + s * 32 + ((cq * 4) & 31)];
  float4 t0 = tb[0], t1 = tb[1];
  size_t off = (size_t)row * 3072 + 1024 + cq * 8;
  short8 v = *(short8*)(qkv + off);
  *(short8*)(qkv + off) = rope8(v, t0, t1);
}

// ---------------- causal flash attention: merged complementary q-tiles ---------------
// 512 blocks x 512 threads. Block (bh, qp) carries BOTH q-tile (15-qp)*128 (H) and
// qp*128 (L) through ONE KV loop of NT = 32-2qp tiles (L's range is a prefix of H's).
__global__ __launch_bounds__(512, 4) void k_attn(const unsigned short* __restrict__ qkv,
                                                 unsigned short* __restrict__ O) {
  __shared__ unsigned short lK[2][64 * 64];  // [krow][dk] bytes, XOR-swizzled
  __shared__ uint32_t lV32[2][64 * 36];      // V^T [d][col32], sigma-ordered + swizzled

  const int tid = threadIdx.x, w = tid >> 6, lane = tid & 63;
  const int l15 = lane & 15, lg = lane >> 4;
  const int slot = (int)blockIdx.x;
  const int f0 = (slot & 7) * 64 + (slot >> 3);  // XCD k: f0 in [64k, 64k+64)
  const int bh = f0 >> 3, qp = f0 & 7;           // 8 bh per XCD -> KV set = one L2
  const int b = bh >> 4, h = bh & 15;
  const size_t rstride = 3072;

  const int qbH = (15 - qp) * 128, qbL = qp * 128;
  const int NT = (qbH >> 6) + 2;       // 32 - 2qp staged tiles
  const int DL = (qbL >> 6) + 1;       // L active while t <= DL

  short8 vr;

  auto stageK = [&](int buf, int t) {
    int fb = tid * 16;
    int r = fb >> 7;
    int cb = (fb ^ ((r & 7) << 4)) & 127;
    gload16((const char*)qkv + ((size_t)(b * S_LEN + t * 64 + r) * rstride + 1024 + h * 64) * 2 + cb,
            (char*)(&lK[buf][0]) + fb);
  };
  auto loadV = [&](int t) {
    int kp = tid >> 4, sub = tid & 15;
    int pp = sub & 1, c = (sub >> 1) * 8;
    vr = *(const short8*)(qkv + (size_t)(b * S_LEN + t * 64 + kp * 2 + pp) * rstride + 2048 + h * 64 + c);
  };
  auto writeV = [&](int buf) {
    int kp = tid >> 4, sub = tid & 15;
    int pp = sub & 1, c = (sub >> 1) * 8;
    uint32_t u0 = __shfl_xor(((const uint32_t*)&vr)[0], 1);
    uint32_t u1 = __shfl_xor(((const uint32_t*)&vr)[1], 1);
    uint32_t u2 = __shfl_xor(((const uint32_t*)&vr)[2], 1);
    uint32_t u3 = __shfl_xor(((const uint32_t*)&vr)[3], 1);
    unsigned short ov[8];
    ((uint32_t*)ov)[0] = u0; ((uint32_t*)ov)[1] = u1;
    ((uint32_t*)ov)[2] = u2; ((uint32_t*)ov)[3] = u3;
    const unsigned short* own = (const unsigned short*)&vr;
    int colk = ((kp >> 4) << 4) | (((kp >> 1) & 3) << 2) | (((kp >> 3) & 1) << 1) | (kp & 1);
#pragma unroll
    for (int j = 0; j < 4; ++j) {
      int d = c + (pp ? 4 : 0) + j;
      unsigned short lo = pp ? ov[4 + j] : own[j];
      unsigned short hi = pp ? own[4 + j] : ov[j];
      uint32_t packed = (uint32_t)lo | ((uint32_t)hi << 16);
      int colS = colk ^ (((d >> 3) & 7) << 2);
      lV32[buf][d * 36 + colS] = packed;
    }
  };

  short8 ones;
#pragma unroll
  for (int e = 0; e < 8; ++e) ones[e] = (short)0x3F80;  // bf16 1.0

  const int qrowH = qbH + w * 16 + l15;
  const int qrowL = qbL + w * 16 + l15;

  // Q fragments: load + RoPE in-register (Q table pre-scaled by 1/8*log2e)
  short8 qfH[2], qfL[2];
  {
    const unsigned short* qh = qkv + (size_t)(b * S_LEN + qrowH) * rstride + h * 64 + lg * 8;
    const unsigned short* ql = qkv + (size_t)(b * S_LEN + qrowL) * rstride + h * 64 + lg * 8;
    const float4* th0 = (const float4*)&g_tab[qrowH * 32 + lg * 4];
    const float4* th1 = (const float4*)&g_tab[qrowH * 32 + 16 + lg * 4];
    const float4* tl0 = (const float4*)&g_tab[qrowL * 32 + lg * 4];
    const float4* tl1 = (const float4*)&g_tab[qrowL * 32 + 16 + lg * 4];
    qfH[0] = rope8(*(const short8*)qh, th0[0], th0[1]);
    qfH[1] = rope8(*(const short8*)(qh + 32), th1[0], th1[1]);
    qfL[0] = rope8(*(const short8*)ql, tl0[0], tl0[1]);
    qfL[1] = rope8(*(const short8*)(ql + 32), tl1[0], tl1[1]);
  }

  float mrunH = 0.f, mrunL = 0.f;
  f32x4 oaccH[4] = {}, oaccL[4] = {};
  f32x4 csumH = {}, csumL = {};

  stageK(0, 0);
  loadV(0);
  writeV(0);
  __syncthreads();

  for (int t = 0; t < NT; ++t) {
    const int cur = t & 1, nxt = cur ^ 1;
    const bool more = (t + 1 < NT);
    if (more) { stageK(nxt, t + 1); loadV(t + 1); }  // issue-early

    const bool actL = (t <= DL);   // wave-uniform (block-uniform, in fact)

    // QK^T swapped, shared K fragments: sf = mfma(K, Q)
    f32x4 sfH[4] = {}, sfL[4] = {};
    __builtin_amdgcn_s_setprio(1);
    if (actL) {
#pragma unroll
      for (int ks = 0; ks < 2; ++ks)
#pragma unroll
        for (int jf = 0; jf < 4; ++jf) {
          int krow = jf * 16 + l15;
          int g = krow * 128 + ks * 64 + lg * 16;
          int a = g ^ ((krow & 7) << 4);
          short8 kb = *(const short8*)((const char*)(&lK[cur][0]) + a);
          sfH[jf] = __builtin_amdgcn_mfma_f32_16x16x32_bf16(kb, qfH[ks], sfH[jf], 0, 0, 0);
          sfL[jf] = __builtin_amdgcn_mfma_f32_16x16x32_bf16(kb, qfL[ks], sfL[jf], 0, 0, 0);
        }
    } else {
#pragma unroll
      for (int ks = 0; ks < 2; ++ks)
#pragma unroll
        for (int jf = 0; jf < 4; ++jf) {
          int krow = jf * 16 + l15;
          int g = krow * 128 + ks * 64 + lg * 16;
          int a = g ^ ((krow & 7) << 4);
          short8 kb = *(const short8*)((const char*)(&lK[cur][0]) + a);
          sfH[jf] = __builtin_amdgcn_mfma_f32_16x16x32_bf16(kb, qfH[ks], sfH[jf], 0, 0, 0);
        }
    }
    __builtin_amdgcn_s_setprio(0);

    // softmax + PV for one context (maxless, log2 domain)
    auto sm_pv = [&](f32x4 (&sf)[4], float& mrun, f32x4 (&oacc)[4], f32x4& csum, int qrow) {
      const bool dg = (t * 64 + 63 > qrow - l15 + (w & 0) * 0 + 0 * 64) && (t * 64 + 63 > ((qrow / 16) * 16));
      float pv[4][4];
#pragma unroll
      for (int jf = 0; jf < 4; ++jf)
#pragma unroll
        for (int r = 0; r < 4; ++r) {
          float v = sf[jf][r];
          if (dg) {
            int kglob = t * 64 + jf * 16 + lg * 4 + r;
            if (kglob > qrow) v = -3e38f;
          }
          pv[jf][r] = v;
        }
      if (t == 0) {
        float mx = -3e38f;
#pragma unroll
        for (int jf = 0; jf < 4; ++jf)
#pragma unroll
          for (int r = 0; r < 4; ++r) mx = fmaxf(mx, pv[jf][r]);
        mx = fmaxf(mx, __shfl_xor(mx, 16));
        mx = fmaxf(mx, __shfl_xor(mx, 32));
        mrun = mx;
      }
#pragma unroll
      for (int jf = 0; jf < 4; ++jf)
#pragma unroll
        for (int r = 0; r < 4; ++r)
          pv[jf][r] = exp2f(pv[jf][r] - mrun);

      __builtin_amdgcn_s_setprio(1);
#pragma unroll
      for (int ks = 0; ks < 2; ++ks) {
        union { uint32_t u[4]; short8 v; } pb;
        pb.u[0] = pk2bf(pv[2 * ks][0], pv[2 * ks][1]);
        pb.u[1] = pk2bf(pv[2 * ks][2], pv[2 * ks][3]);
        pb.u[2] = pk2bf(pv[2 * ks + 1][0], pv[2 * ks + 1][1]);
        pb.u[3] = pk2bf(pv[2 * ks + 1][2], pv[2 * ks + 1][3]);
#pragma unroll
        for (int j = 0; j < 4; ++j) {
          int d = j * 16 + l15;
          int colS = (ks * 16 + lg * 4) ^ (((d >> 3) & 7) << 2);
          short8 vb = *(const short8*)(&lV32[cur][d * 36 + colS]);
          oacc[j] = __builtin_amdgcn_mfma_f32_16x16x32_bf16(vb, pb.v, oacc[j], 0, 0, 0);
        }
        csum = __builtin_amdgcn_mfma_f32_16x16x32_bf16(ones, pb.v, csum, 0, 0, 0);
      }
      __builtin_amdgcn_s_setprio(0);
    };

    sm_pv(sfH, mrunH, oaccH, csumH, qrowH);
    if (actL) sm_pv(sfL, mrunL, oaccL, csumL, qrowL);

    if (more) writeV(nxt);  // write-late
    __syncthreads();

    // overflow guards (never taken for N(0,1)-scale data)
    if (!__all(csumH[0] <= 1.0e9f)) {
      const float al = 0x1p-32f;
#pragma unroll
      for (int j = 0; j < 4; ++j)
#pragma unroll
        for (int r = 0; r < 4; ++r) oaccH[j][r] *= al;
#pragma unroll
      for (int r = 0; r < 4; ++r) csumH[r] *= al;
      mrunH += 32.0f;
    }
    if (!__all(csumL[0] <= 1.0e9f)) {
      const float al = 0x1p-32f;
#pragma unroll
      for (int j = 0; j < 4; ++j)
#pragma unroll
        for (int r = 0; r < 4; ++r) oaccL[j][r] *= al;
#pragma unroll
      for (int r = 0; r < 4; ++r) csumL[r] *= al;
      mrunL += 32.0f;
    }
  }

  // O write: lane owns one q-row per context; d = j*16 + lg*4 + r
  {
    float rinv = __builtin_amdgcn_rcpf(csumH[0]);
    unsigned short* orow = O + (size_t)(b * S_LEN + qrowH) * 1024 + h * 64;
#pragma unroll
    for (int j = 0; j < 4; ++j) {
      union { uint32_t u[2]; u16x4 v; } ow;
      ow.u[0] = pk2bf(oaccH[j][0] * rinv, oaccH[j][1] * rinv);
      ow.u[1] = pk2bf(oaccH[j][2] * rinv, oaccH[j][3] * rinv);
      *(u16x4*)(orow + j * 16 + lg * 4) = ow.v;
    }
  }
  {
    float rinv = __builtin_amdgcn_rcpf(csumL[0]);
    unsigned short* orow = O + (size_t)(b * S_LEN + qrowL) * 1024 + h * 64;
#pragma unroll
    for (int j = 0; j < 4; ++j) {
      union { uint32_t u[2]; u16x4 v; } ow;
      ow.u[0] = pk2bf(oaccL[j][0] * rinv, oaccL[j][1] * rinv);
      ow.u[1] = pk2bf(oaccL[j][2] * rinv, oaccL[j][3] * rinv);
      *(u16x4*)(orow + j * 16 + lg * 4) = ow.v;
    }
  }
}

extern "C" void kernel_launch(void* const* d_in, const int* in_sizes, int n_in,
                              void* d_out, int out_size, void* d_ws, size_t ws_size,
                              hipStream_t stream) {
  const float* x  = (const float*)d_in[0];
  const int* pos  = (const int*)d_in[1];
  const float* wq = (const float*)d_in[2];
  const float* wk = (const float*)d_in[3];
  const float* wv = (const float*)d_in[4];
  const float* wo = (const float*)d_in[5];
  float* out = (float*)d_out;

  char* ws = (char*)d_ws;
  unsigned short* xb   = (unsigned short*)(ws);                              // 16 MB
  unsigned short* wqkv = (unsigned short*)(ws + (size_t)16 * 1024 * 1024);   // 6 MB
  unsigned short* wob  = (unsigned short*)(ws + (size_t)22 * 1024 * 1024);   // 2 MB
  unsigned short* qkv  = (unsigned short*)(ws + (size_t)24 * 1024 * 1024);   // 48 MB
  unsigned short* ob   = (unsigned short*)(ws + (size_t)72 * 1024 * 1024);   // 16 MB

  // prep: x->bf16 | weights->bf16 | rope tables (one launch)
  k_prep<<<12544, 256, 0, stream>>>(x, wq, wk, wv, wo, pos, xb, wqkv);

  // fused QKV projection (prefetch-pipelined)
  k_gemm_nt<0><<<1536, 256, 0, stream>>>(xb, wqkv, qkv, 1024, 3072, 24);

  // RoPE on K only (Q roped in-register inside k_attn)
  k_rope<<<4096, 256, 0, stream>>>(qkv);

  // causal flash attention (merged complementary q-tiles)
  k_attn<<<512, 512, 0, stream>>>(qkv, ob);

  // output projection
  k_gemm_nt<1><<<512, 256, 0, stream>>>(ob, wob, out, 1024, 1024, 8);
}

// Round 12
// 284.089 us; speedup vs baseline: 1.6761x; 1.6761x over previous
//
#include <hip/hip_runtime.h>
#include <hip/hip_bf16.h>
#include <stdint.h>

#define S_LEN 2048
#define NHEAD 16
#define BATCH 4

typedef __attribute__((ext_vector_type(8))) short short8;
typedef __attribute__((ext_vector_type(4))) float f32x4;
typedef __attribute__((ext_vector_type(4))) unsigned short u16x4;

__device__ float2 g_tab[131072];  // [0..64K) Q table (pre-scaled), [64K..128K) K table

__device__ __forceinline__ unsigned short f2bf(float f) {
  union { float f; uint32_t u; } a; a.f = f;
  uint32_t r = (a.u + 0x7fff + ((a.u >> 16) & 1)) >> 16;
  return (unsigned short)r;
}
__device__ __forceinline__ float bf2f(unsigned short u) {
  union { uint32_t u; float f; } a; a.u = ((uint32_t)u) << 16;
  return a.f;
}
__device__ __forceinline__ uint32_t pk2bf(float a, float b) {
  union { __hip_bfloat162 h; uint32_t u; } cv;
  cv.h = __float22bfloat162_rn(float2{a, b});
  return cv.u;
}

__device__ __forceinline__ void gload16(const void* g, void* l) {
  __builtin_amdgcn_global_load_lds(
      (const __attribute__((address_space(1))) void*)g,
      (__attribute__((address_space(3))) void*)l, 16, 0, 0);
}

// rotate 8 bf16 (4 adjacent pairs) by table entries t01 (pairs 0,1) t23 (pairs 2,3)
__device__ __forceinline__ short8 rope8(short8 v, float4 t01, float4 t23) {
  float x0 = bf2f((unsigned short)v[0]), x1 = bf2f((unsigned short)v[1]);
  float x2 = bf2f((unsigned short)v[2]), x3 = bf2f((unsigned short)v[3]);
  float x4 = bf2f((unsigned short)v[4]), x5 = bf2f((unsigned short)v[5]);
  float x6 = bf2f((unsigned short)v[6]), x7 = bf2f((unsigned short)v[7]);
  union { uint32_t u[4]; short8 v; } o;
  o.u[0] = pk2bf(t01.x * x0 - t01.y * x1, t01.y * x0 + t01.x * x1);
  o.u[1] = pk2bf(t01.z * x2 - t01.w * x3, t01.w * x2 + t01.z * x3);
  o.u[2] = pk2bf(t23.x * x4 - t23.y * x5, t23.y * x4 + t23.x * x5);
  o.u[3] = pk2bf(t23.z * x6 - t23.w * x7, t23.w * x6 + t23.z * x7);
  return o.v;
}

// ---------------- prep: x->bf16, weights->bf16, rope tables, one launch -------------
__global__ void k_prep(const float* __restrict__ x, const float* __restrict__ wq,
                       const float* __restrict__ wk, const float* __restrict__ wv,
                       const float* __restrict__ wo, const int* __restrict__ pos,
                       unsigned short* __restrict__ xb, unsigned short* __restrict__ wdst) {
  int bid = blockIdx.x;
  if (bid < 8192) {
    int i = bid * 256 + threadIdx.x;
    float4 v = ((const float4*)x)[i];
    union { uint32_t u[2]; u16x4 v; } o;
    o.u[0] = pk2bf(v.x, v.y);
    o.u[1] = pk2bf(v.z, v.w);
    ((u16x4*)xb)[i] = o.v;
  } else if (bid < 12288) {
    int i = (bid - 8192) * 256 + threadIdx.x;
    int r = i >> 18;
    const float* s = r == 0 ? wq : r == 1 ? wk : r == 2 ? wv : wo;
    float4 v = ((const float4*)s)[i & 0x3FFFF];
    union { uint32_t u[2]; u16x4 v; } o;
    o.u[0] = pk2bf(v.x, v.y);
    o.u[1] = pk2bf(v.z, v.w);
    ((u16x4*)wdst)[i] = o.v;
  } else {
    int i = (bid - 12288) * 256 + threadIdx.x;
    int s = i >> 5, p = i & 31;
    float fp = (float)pos[s];
    float inv = exp2f(-(float)p * 0.41524101186092029f);
    float sn, cs;
    __sincosf(fp * inv, &sn, &cs);
    const float SCL = 0.18033688011112042f;  // (1/8) * log2(e)
    g_tab[i] = float2{cs * SCL, sn * SCL};
    g_tab[65536 + i] = float2{cs, sn};
  }
}

// ---------------- NT GEMM, XCD-swizzled, 1-deep prefetch double-buffer --------------
template<int OUTF32>
__global__ __launch_bounds__(256) void k_gemm_nt(
    const unsigned short* __restrict__ A, const unsigned short* __restrict__ B,
    void* __restrict__ Cp, int K, int ldc, int gx)
{
  __shared__ unsigned short lA[2][128 * 64];
  __shared__ unsigned short lB[2][128 * 64];
  const int tid = threadIdx.x;
  const int w = tid >> 6, lane = tid & 63;
  const int wm = w >> 1, wn = w & 1;
  const int l15 = lane & 15, lg = lane >> 4;
  const int nwg = (int)gridDim.x, slot = (int)blockIdx.x;
  const int f = (slot & 7) * (nwg >> 3) + (slot >> 3);
  const int row0 = (f / gx) * 128, col0 = (f % gx) * 128;

  f32x4 acc[4][4] = {};
  const size_t rsb = (size_t)K * 2;

  auto stage = [&](int buf, int k0) {
#pragma unroll
    for (int it = 0; it < 4; ++it) {
      int fb = w * 4096 + it * 1024 + lane * 16;
      int r = fb >> 7, cb = fb & 127;
      gload16((const char*)A + (size_t)(row0 + r) * rsb + k0 * 2 + cb,
              (char*)(&lA[buf][0]) + (w * 4096 + it * 1024));
      gload16((const char*)B + (size_t)(col0 + r) * rsb + k0 * 2 + cb,
              (char*)(&lB[buf][0]) + (w * 4096 + it * 1024));
    }
  };

  const int nk = K >> 6;
  stage(0, 0);
  __syncthreads();

  for (int t = 0; t < nk; ++t) {
    const int cur = t & 1;
    if (t + 1 < nk) stage(cur ^ 1, (t + 1) * 64);

#pragma unroll
    for (int ks = 0; ks < 2; ++ks) {
      short8 af[4], bg[4];
#pragma unroll
      for (int i = 0; i < 4; ++i) {
        int rowa = wm * 64 + i * 16 + l15;
        af[i] = *(const short8*)((const char*)(&lA[cur][0]) + rowa * 128 + ks * 64 + lg * 16);
        int rowb = wn * 64 + i * 16 + l15;
        bg[i] = *(const short8*)((const char*)(&lB[cur][0]) + rowb * 128 + ks * 64 + lg * 16);
      }
#pragma unroll
      for (int i = 0; i < 4; ++i)
#pragma unroll
        for (int j = 0; j < 4; ++j)
          acc[i][j] = __builtin_amdgcn_mfma_f32_16x16x32_bf16(af[i], bg[j], acc[i][j], 0, 0, 0);
    }
    __syncthreads();
  }

#pragma unroll
  for (int i = 0; i < 4; ++i)
#pragma unroll
    for (int j = 0; j < 4; ++j) {
      int col = col0 + wn * 64 + j * 16 + l15;
#pragma unroll
      for (int r = 0; r < 4; ++r) {
        int row = row0 + wm * 64 + i * 16 + lg * 4 + r;
        float v = acc[i][j][r];
        if (OUTF32) ((float*)Cp)[(size_t)row * ldc + col] = v;
        else ((unsigned short*)Cp)[(size_t)row * ldc + col] = f2bf(v);
      }
    }
}

// ---------------- RoPE apply, K only (Q is roped in-register inside k_attn) ---------
__global__ void k_rope(unsigned short* __restrict__ qkv) {
  int idx = blockIdx.x * 256 + threadIdx.x;   // 1M threads: 8192 rows x 128 quads
  int row = idx >> 7;
  int cq = idx & 127;
  int s = row & (S_LEN - 1);
  const float4* tb = (const float4*)&g_tab[65536 + s * 32 + ((cq * 4) & 31)];
  float4 t0 = tb[0], t1 = tb[1];
  size_t off = (size_t)row * 3072 + 1024 + cq * 8;
  short8 v = *(short8*)(qkv + off);
  *(short8*)(qkv + off) = rope8(v, t0, t1);
}

// ---------------- causal flash attention: paired q-tiles, maxless softmax, MFMA-sum --
// 512 blocks x 512 threads. Block (bh, qp) does q-tiles (15-qp)*128 then qp*128.
__global__ __launch_bounds__(512) void k_attn(const unsigned short* __restrict__ qkv,
                                              unsigned short* __restrict__ O) {
  __shared__ unsigned short lK[2][64 * 64];  // [krow][dk] bytes, XOR-swizzled
  __shared__ uint32_t lV32[2][64 * 36];      // V^T [d][col32], sigma-ordered + swizzled

  const int tid = threadIdx.x, w = tid >> 6, lane = tid & 63;
  const int l15 = lane & 15, lg = lane >> 4;
  const int slot = (int)blockIdx.x;
  const int f0 = (slot & 7) * 64 + (slot >> 3);  // XCD k: f0 in [64k, 64k+64)
  const int bh = f0 >> 3, qp = f0 & 7;           // 8 bh per XCD -> KV set = one L2
  const int b = bh >> 4, h = bh & 15;
  const size_t rstride = 3072;

  short8 vr;

  auto stageK = [&](int buf, int t) {
    int fb = tid * 16;
    int r = fb >> 7;
    int cb = (fb ^ ((r & 7) << 4)) & 127;
    gload16((const char*)qkv + ((size_t)(b * S_LEN + t * 64 + r) * rstride + 1024 + h * 64) * 2 + cb,
            (char*)(&lK[buf][0]) + fb);
  };
  auto loadV = [&](int t) {
    int kp = tid >> 4, sub = tid & 15;
    int pp = sub & 1, c = (sub >> 1) * 8;
    vr = *(const short8*)(qkv + (size_t)(b * S_LEN + t * 64 + kp * 2 + pp) * rstride + 2048 + h * 64 + c);
  };
  auto writeV = [&](int buf) {
    int kp = tid >> 4, sub = tid & 15;
    int pp = sub & 1, c = (sub >> 1) * 8;
    uint32_t u0 = __shfl_xor(((const uint32_t*)&vr)[0], 1);
    uint32_t u1 = __shfl_xor(((const uint32_t*)&vr)[1], 1);
    uint32_t u2 = __shfl_xor(((const uint32_t*)&vr)[2], 1);
    uint32_t u3 = __shfl_xor(((const uint32_t*)&vr)[3], 1);
    unsigned short ov[8];
    ((uint32_t*)ov)[0] = u0; ((uint32_t*)ov)[1] = u1;
    ((uint32_t*)ov)[2] = u2; ((uint32_t*)ov)[3] = u3;
    const unsigned short* own = (const unsigned short*)&vr;
    int colk = ((kp >> 4) << 4) | (((kp >> 1) & 3) << 2) | (((kp >> 3) & 1) << 1) | (kp & 1);
#pragma unroll
    for (int j = 0; j < 4; ++j) {
      int d = c + (pp ? 4 : 0) + j;
      unsigned short lo = pp ? ov[4 + j] : own[j];
      unsigned short hi = pp ? own[4 + j] : ov[j];
      uint32_t packed = (uint32_t)lo | ((uint32_t)hi << 16);
      int colS = colk ^ (((d >> 3) & 7) << 2);
      lV32[buf][d * 36 + colS] = packed;
    }
  };

  short8 ones;
#pragma unroll
  for (int e = 0; e < 8; ++e) ones[e] = (short)0x3F80;  // bf16 1.0

  for (int seg = 0; seg < 2; ++seg) {
    const int qb = (seg == 0 ? (15 - qp) : qp) * 128;
    const int ntiles = (qb >> 6) + 2;
    const int qrow = qb + w * 16 + l15;

    // Q fragments: load + RoPE in-register (Q table pre-scaled by 1/8*log2e)
    short8 qf[2];
    {
      const unsigned short* qpt = qkv + (size_t)(b * S_LEN + qrow) * rstride + h * 64 + lg * 8;
      const float4* t0p = (const float4*)&g_tab[qrow * 32 + lg * 4];
      const float4* t1p = (const float4*)&g_tab[qrow * 32 + 16 + lg * 4];
      qf[0] = rope8(*(const short8*)qpt, t0p[0], t0p[1]);
      qf[1] = rope8(*(const short8*)(qpt + 32), t1p[0], t1p[1]);
    }

    float mrun = 0.f;
    f32x4 oacc[4] = {};
    f32x4 csum = {};

    stageK(0, 0);
    loadV(0);
    writeV(0);
    __syncthreads();

    for (int t = 0; t < ntiles; ++t) {
      const int cur = t & 1, nxt = cur ^ 1;
      const bool more = (t + 1 < ntiles);
      if (more) { stageK(nxt, t + 1); loadV(t + 1); }  // issue-early

      // QK^T swapped: mfma(A=K, B=Q) -> lane holds q=l15, k-slot = jf*16+lg*4+r
      f32x4 sf[4] = {};
      __builtin_amdgcn_s_setprio(1);
#pragma unroll
      for (int ks = 0; ks < 2; ++ks) {
#pragma unroll
        for (int jf = 0; jf < 4; ++jf) {
          int krow = jf * 16 + l15;
          int g = krow * 128 + ks * 64 + lg * 16;
          int a = g ^ ((krow & 7) << 4);
          short8 kb = *(const short8*)((const char*)(&lK[cur][0]) + a);
          sf[jf] = __builtin_amdgcn_mfma_f32_16x16x32_bf16(kb, qf[ks], sf[jf], 0, 0, 0);
        }
      }
      __builtin_amdgcn_s_setprio(0);

      // mask + maxless softmax (log2 domain, Q pre-scaled)
      const int kv = t * 64;
      const bool dg = (kv + 63 > qb + w * 16);
      float pv[4][4];
#pragma unroll
      for (int jf = 0; jf < 4; ++jf)
#pragma unroll
        for (int r = 0; r < 4; ++r) {
          float v = sf[jf][r];
          if (dg) {
            int kglob = kv + jf * 16 + lg * 4 + r;
            if (kglob > qrow) v = -3e38f;
          }
          pv[jf][r] = v;
        }
      if (t == 0) {  // establish the log2 origin once per segment
        float mx = -3e38f;
#pragma unroll
        for (int jf = 0; jf < 4; ++jf)
#pragma unroll
          for (int r = 0; r < 4; ++r) mx = fmaxf(mx, pv[jf][r]);
        mx = fmaxf(mx, __shfl_xor(mx, 16));
        mx = fmaxf(mx, __shfl_xor(mx, 32));
        mrun = mx;
      }
#pragma unroll
      for (int jf = 0; jf < 4; ++jf)
#pragma unroll
        for (int r = 0; r < 4; ++r)
          pv[jf][r] = exp2f(pv[jf][r] - mrun);

      // PV swapped + ones-row sum: O^T[d][q] += V^T[d][k] P^T[k][q]; csum += 1^T P^T
      __builtin_amdgcn_s_setprio(1);
#pragma unroll
      for (int ks = 0; ks < 2; ++ks) {
        union { uint32_t u[4]; short8 v; } pb;
        pb.u[0] = pk2bf(pv[2 * ks][0], pv[2 * ks][1]);
        pb.u[1] = pk2bf(pv[2 * ks][2], pv[2 * ks][3]);
        pb.u[2] = pk2bf(pv[2 * ks + 1][0], pv[2 * ks + 1][1]);
        pb.u[3] = pk2bf(pv[2 * ks + 1][2], pv[2 * ks + 1][3]);
#pragma unroll
        for (int j = 0; j < 4; ++j) {
          int d = j * 16 + l15;
          int colS = (ks * 16 + lg * 4) ^ (((d >> 3) & 7) << 2);
          short8 vb = *(const short8*)(&lV32[cur][d * 36 + colS]);
          oacc[j] = __builtin_amdgcn_mfma_f32_16x16x32_bf16(vb, pb.v, oacc[j], 0, 0, 0);
        }
        csum = __builtin_amdgcn_mfma_f32_16x16x32_bf16(ones, pb.v, csum, 0, 0, 0);
      }
      __builtin_amdgcn_s_setprio(0);

      if (more) writeV(nxt);  // write-late
      __syncthreads();

      // overflow guard (never taken for N(0,1)-scale data): shift the log2 origin
      if (!__all(csum[0] <= 1.0e9f)) {
        const float al = 0x1p-32f;
#pragma unroll
        for (int j = 0; j < 4; ++j)
#pragma unroll
          for (int r = 0; r < 4; ++r) oacc[j][r] *= al;
#pragma unroll
        for (int r = 0; r < 4; ++r) csum[r] *= al;
        mrun += 32.0f;
      }
    }

    // O write: lane owns one q-row; d = j*16 + lg*4 + r (contiguous quads)
    float rinv = __builtin_amdgcn_rcpf(csum[0]);
    unsigned short* orow = O + (size_t)(b * S_LEN + qrow) * 1024 + h * 64;
#pragma unroll
    for (int j = 0; j < 4; ++j) {
      union { uint32_t u[2]; u16x4 v; } ow;
      ow.u[0] = pk2bf(oacc[j][0] * rinv, oacc[j][1] * rinv);
      ow.u[1] = pk2bf(oacc[j][2] * rinv, oacc[j][3] * rinv);
      *(u16x4*)(orow + j * 16 + lg * 4) = ow.v;
    }
  }
}

extern "C" void kernel_launch(void* const* d_in, const int* in_sizes, int n_in,
                              void* d_out, int out_size, void* d_ws, size_t ws_size,
                              hipStream_t stream) {
  const float* x  = (const float*)d_in[0];
  const int* pos  = (const int*)d_in[1];
  const float* wq = (const float*)d_in[2];
  const float* wk = (const float*)d_in[3];
  const float* wv = (const float*)d_in[4];
  const float* wo = (const float*)d_in[5];
  float* out = (float*)d_out;

  char* ws = (char*)d_ws;
  unsigned short* xb   = (unsigned short*)(ws);                              // 16 MB
  unsigned short* wqkv = (unsigned short*)(ws + (size_t)16 * 1024 * 1024);   // 6 MB
  unsigned short* wob  = (unsigned short*)(ws + (size_t)22 * 1024 * 1024);   // 2 MB
  unsigned short* qkv  = (unsigned short*)(ws + (size_t)24 * 1024 * 1024);   // 48 MB
  unsigned short* ob   = (unsigned short*)(ws + (size_t)72 * 1024 * 1024);   // 16 MB

  // prep: x->bf16 | weights->bf16 | rope tables (one launch)
  k_prep<<<12544, 256, 0, stream>>>(x, wq, wk, wv, wo, pos, xb, wqkv);

  // fused QKV projection (prefetch-pipelined)
  k_gemm_nt<0><<<1536, 256, 0, stream>>>(xb, wqkv, qkv, 1024, 3072, 24);

  // RoPE on K only (Q roped in-register inside k_attn)
  k_rope<<<4096, 256, 0, stream>>>(qkv);

  // causal flash attention (paired q-tiles)
  k_attn<<<512, 512, 0, stream>>>(qkv, ob);

  // output projection
  k_gemm_nt<1><<<512, 256, 0, stream>>>(ob, wob, out, 1024, 1024, 8);
}